// Round 8
// baseline (1248.093 us; speedup 1.0000x reference)
//
#include <hip/hip_runtime.h>
#include <hip/hip_bf16.h>
#include <cstdint>
#include <cstddef>

#define VV 50000
#define HH 1024
#define NROWS 4096
#define VPAD 50176      // padded reordered-W rows
#define SP1 4000
#define SP2 20000
#define SP3 50000

#define BM 256
#define BN 128
#define BK 128
#define NKT (HH / BK)           // 8
#define A_SLOT_B (BM * BK)      // 32768 bytes (fp8)
#define B_SLOT_B (BN * BK)      // 16384 bytes
#define SLOT_B (A_SLOT_B + B_SLOT_B)  // 49152 B/slot, 3 slots = 144 KiB

// reordered-W column map: [0..3999]=weight, [4000..4001]=tail_vectors,
// [4002..50001]=weight[4000..49999], rest zero-pad
#define CB_T1 4002
#define CB_T2 20002
#define CL_HEAD 4002
#define CL_T1 20002
#define CL_T2 50002
#define CT_HEAD 32
#define CT_T1 125
#define CT_T2 235
#define PH_STRIDE 64    // 2*CT_HEAD
#define PT1_STRIDE 250  // 2*CT_T1
#define PT2_STRIDE 470  // 2*CT_T2

#define WSCALE 256.0f
#define HSCALE 16.0f
#define INVSCALE (1.0f / 4096.0f)
#define UNIT_SCALE 0x7f7f7f7fu  // E8M0 1.0 in every byte

typedef __attribute__((ext_vector_type(4))) int i32x4;
typedef __attribute__((ext_vector_type(8))) int i32x8;
typedef __attribute__((ext_vector_type(4))) float f32x4;

typedef __attribute__((address_space(1))) unsigned int uint_g;
typedef __attribute__((address_space(3))) unsigned int uint_l;

__device__ __forceinline__ void gload16(const void* g, void* l) {
  __builtin_amdgcn_global_load_lds((const uint_g*)g, (uint_l*)l, 16, 0, 0);
}

// pack 4 floats -> 4 fp8 e4m3 bytes
__device__ __forceinline__ unsigned int pk4(float a, float b, float c, float d) {
  int p = __builtin_amdgcn_cvt_pk_fp8_f32(a, b, 0, 0);
  p = __builtin_amdgcn_cvt_pk_fp8_f32(c, d, p, 1);
  return (unsigned int)p;
}

// ---- convert weight + tail_vectors -> fp8 (x256), reordered rows ----
__global__ void convW(const float* __restrict__ w, const float* __restrict__ tails,
                      unsigned char* __restrict__ Wf) {
  const size_t nq = (size_t)VPAD * HH / 4;
  for (size_t q = (size_t)blockIdx.x * blockDim.x + threadIdx.x; q < nq;
       q += (size_t)gridDim.x * blockDim.x) {
    const size_t e = q * 4;
    const int row = (int)(e >> 10);
    unsigned int o;
    if (row < 4000) {
      float4 f = *(const float4*)(w + e);
      o = pk4(f.x * WSCALE, f.y * WSCALE, f.z * WSCALE, f.w * WSCALE);
    } else if (row < 4002) {
      float4 f = *(const float4*)(tails + (e - (size_t)4000 * HH));
      o = pk4(f.x * WSCALE, f.y * WSCALE, f.z * WSCALE, f.w * WSCALE);
    } else if (row < 50002) {
      float4 f = *(const float4*)(w + (e - 2048));
      o = pk4(f.x * WSCALE, f.y * WSCALE, f.z * WSCALE, f.w * WSCALE);
    } else {
      o = 0u;
    }
    *(unsigned int*)(Wf + e) = o;
  }
}

// reordered bias (pads get -1e30 so exp() underflows to 0)
__global__ void biasK(const float* __restrict__ bias, const float* __restrict__ tb,
                      float* __restrict__ biasr) {
  const int r = blockIdx.x * 256 + threadIdx.x;
  if (r >= VPAD) return;
  float v;
  if (r < 4000) v = bias[r];
  else if (r == 4000) v = tb[0];
  else if (r == 4001) v = tb[1];
  else if (r < 50002) v = bias[r - 2];
  else v = -1e30f;
  biasr[r] = v;
}

__global__ void convH(const float* __restrict__ h, unsigned char* __restrict__ Hf) {
  const size_t nq = (size_t)NROWS * HH / 4;
  for (size_t q = (size_t)blockIdx.x * blockDim.x + threadIdx.x; q < nq;
       q += (size_t)gridDim.x * blockDim.x) {
    const size_t e = q * 4;
    float4 f = *(const float4*)(h + e);
    *(unsigned int*)(Hf + e) =
        pk4(f.x * HSCALE, f.y * HSCALE, f.z * HSCALE, f.w * HSCALE);
  }
}

// ---- deterministic cluster scan: compact index per row, counts ----
__global__ __launch_bounds__(1024) void scanK(const int* __restrict__ targets,
                                              int* __restrict__ cidx,
                                              int* __restrict__ counts) {
  __shared__ int s1[1024], s2[1024];
  const int tid = threadIdx.x;
  int c[4];
  int n1 = 0, n2 = 0;
#pragma unroll
  for (int j = 0; j < 4; j++) {
    const int t = targets[tid * 4 + j];
    c[j] = (t >= SP1) + (t >= SP2);
    n1 += (c[j] == 1);
    n2 += (c[j] == 2);
  }
  s1[tid] = n1;
  s2[tid] = n2;
  __syncthreads();
  for (int off = 1; off < 1024; off <<= 1) {
    const int a1 = (tid >= off) ? s1[tid - off] : 0;
    const int a2 = (tid >= off) ? s2[tid - off] : 0;
    __syncthreads();
    s1[tid] += a1;
    s2[tid] += a2;
    __syncthreads();
  }
  int e1 = s1[tid] - n1, e2 = s2[tid] - n2;
#pragma unroll
  for (int j = 0; j < 4; j++) {
    if (c[j] == 1) cidx[tid * 4 + j] = e1++;
    else if (c[j] == 2) cidx[tid * 4 + j] = e2++;
    else cidx[tid * 4 + j] = 0;
  }
  if (tid == 1023) {
    counts[0] = s1[1023];
    counts[1] = s2[1023];
    counts[2] = NROWS;
  }
}

// zero both compact-H fp8 buffers (contiguous)
__global__ void zeroHc(uint4* __restrict__ Hc) {
  const size_t n16 = (size_t)2 * NROWS * HH / 16;
  const uint4 z = {0u, 0u, 0u, 0u};
  for (size_t i = (size_t)blockIdx.x * blockDim.x + threadIdx.x; i < n16;
       i += (size_t)gridDim.x * blockDim.x)
    Hc[i] = z;
}

// gather fp8 H rows into per-cluster compact matrices (1 wave per row)
__global__ __launch_bounds__(256) void gatherK(const unsigned char* __restrict__ Hf,
                                               const int* __restrict__ targets,
                                               const int* __restrict__ cidx,
                                               unsigned char* __restrict__ Hc1,
                                               unsigned char* __restrict__ Hc2) {
  const int row = blockIdx.x * 4 + (threadIdx.x >> 6);
  const int lane = threadIdx.x & 63;
  const int t = targets[row];
  const int cl = (t >= SP1) + (t >= SP2);
  if (cl == 0) return;
  unsigned char* dst = (cl == 1 ? Hc1 : Hc2) + (size_t)cidx[row] * HH;
  const unsigned char* src = Hf + (size_t)row * HH;
  *(uint4*)(dst + lane * 16) = *(const uint4*)(src + lane * 16);
}

// ---- MX-fp8 GEMM (unit scales) + single-segment sum-exp epilogue ----
// 1-D grid, colTile fastest, trailing early-exit (XCD-balanced).
// 512 threads (8 waves = 4M x 2N, wave 64x64); BK=128, 3-slot LDS ring
// (144 KiB -> 1 block/CU -> 2 waves/SIMD, so VGPR cap 256 is free:
// __launch_bounds__(512, 2)). distance-2 prefetch, counted vmcnt(6),
// XOR-swizzle (R&7)<<4. Register budget: B frags held per tile (32 VGPR),
// A frags streamed one at a time (8 VGPR) -> no spill (round-7 lesson).
__global__ __launch_bounds__(512, 2) void gemm_lse(
    const unsigned char* __restrict__ Ab, const unsigned char* __restrict__ Wf,
    int CT, int colbase, int col_limit, const float* __restrict__ biasr,
    float* __restrict__ partials, const int* __restrict__ Mptr, int mslot) {
  const int Mc = Mptr[mslot];
  const int bid = blockIdx.x;
  const int rowTile = bid / CT;
  const int colTile = bid - rowTile * CT;
  if (rowTile * BM >= Mc) return;

  __shared__ __align__(16) unsigned char lds[3 * SLOT_B];  // 147456 B

  const int tid = threadIdx.x;
  const int w = tid >> 6, lane = tid & 63;
  const int wr = w >> 1, wc = w & 1;
  const int fr = lane & 15, fq = lane >> 4;
  const unsigned char* Ag = Ab + (size_t)rowTile * BM * HH;
  const unsigned char* Bg = Wf + (size_t)(colbase + colTile * BN) * HH;

  // staging source offsets (bytes): linear LDS dest chunk c -> (R=c>>3, j=c&7),
  // global byte = R*HH + k0 + ((j*16) ^ ((R&7)<<4))
  int srcA[4], srcB[2];
#pragma unroll
  for (int i = 0; i < 4; i++) {
    const int c = i * 512 + tid;
    const int R = c >> 3, j = c & 7;
    srcA[i] = R * HH + ((j * 16) ^ ((R & 7) << 4));
  }
#pragma unroll
  for (int i = 0; i < 2; i++) {
    const int c = i * 512 + tid;
    const int R = c >> 3, j = c & 7;
    srcB[i] = R * HH + ((j * 16) ^ ((R & 7) << 4));
  }

  // fragment read offsets (bytes within slot), two b128 per operand frag
  int offA[4][2], offB[4][2];
#pragma unroll
  for (int mi = 0; mi < 4; mi++) {
    const int R = wr * 64 + mi * 16 + fr;
#pragma unroll
    for (int h = 0; h < 2; h++)
      offA[mi][h] = R * BK + ((fq * 32 + h * 16) ^ ((R & 7) << 4));
  }
#pragma unroll
  for (int ni = 0; ni < 4; ni++) {
    const int R = wc * 64 + ni * 16 + fr;
#pragma unroll
    for (int h = 0; h < 2; h++)
      offB[ni][h] = R * BK + ((fq * 32 + h * 16) ^ ((R & 7) << 4));
  }

  f32x4 acc[4][4];
#pragma unroll
  for (int i = 0; i < 4; i++)
#pragma unroll
    for (int j = 0; j < 4; j++) acc[i][j] = (f32x4){0.f, 0.f, 0.f, 0.f};

  auto STAGE = [&](int t) {
    const int slot = t % 3;
    unsigned char* Asl = lds + slot * SLOT_B;
    unsigned char* Bsl = Asl + A_SLOT_B;
    const int k0 = t * BK;  // byte offset (1 B/elem)
#pragma unroll
    for (int i = 0; i < 4; i++)
      gload16(Ag + (size_t)srcA[i] + k0, Asl + (i * 512 + tid) * 16);
#pragma unroll
    for (int i = 0; i < 2; i++)
      gload16(Bg + (size_t)srcB[i] + k0, Bsl + (i * 512 + tid) * 16);
  };

  STAGE(0);
  STAGE(1);

  for (int t = 0; t < NKT; ++t) {
    if (t < NKT - 1)
      asm volatile("s_waitcnt vmcnt(6)" ::: "memory");
    else
      asm volatile("s_waitcnt vmcnt(0)" ::: "memory");
    __builtin_amdgcn_s_barrier();
    if (t + 2 < NKT) STAGE(t + 2);

    const unsigned char* Asl = lds + (t % 3) * SLOT_B;
    const unsigned char* Bsl = Asl + A_SLOT_B;
    // B fragments for the whole tile (32 VGPR)
    i32x8 b8[4];
#pragma unroll
    for (int ni = 0; ni < 4; ni++) {
      i32x4 lo = *(const i32x4*)(Bsl + offB[ni][0]);
      i32x4 hi = *(const i32x4*)(Bsl + offB[ni][1]);
      b8[ni] = __builtin_shufflevector(lo, hi, 0, 1, 2, 3, 4, 5, 6, 7);
    }
    __builtin_amdgcn_s_setprio(1);
#pragma unroll
    for (int mi = 0; mi < 4; mi++) {
      // stream one A fragment (8 VGPR) through 4 MFMAs
      i32x4 lo = *(const i32x4*)(Asl + offA[mi][0]);
      i32x4 hi = *(const i32x4*)(Asl + offA[mi][1]);
      i32x8 a8 = __builtin_shufflevector(lo, hi, 0, 1, 2, 3, 4, 5, 6, 7);
#pragma unroll
      for (int ni = 0; ni < 4; ni++)
        acc[mi][ni] = __builtin_amdgcn_mfma_scale_f32_16x16x128_f8f6f4(
            a8, b8[ni], acc[mi][ni], 0, 0, 0, UNIT_SCALE, 0, UNIT_SCALE);
    }
    __builtin_amdgcn_s_setprio(0);
    __builtin_amdgcn_s_barrier();
  }

  // ---- epilogue: per-(row, 64-col chunk) sum of exp(logit/4096 + bias) ----
  const int colw = colTile * BN + wc * 64;
  float biasv[4];
#pragma unroll
  for (int ni = 0; ni < 4; ni++) {
    const int gcol = colbase + colw + ni * 16 + fr;
    biasv[ni] = (gcol < col_limit) ? biasr[gcol] : -1e30f;
  }
  const int chunk = colTile * 2 + wc;
  const int pstride = CT * 2;

#pragma unroll
  for (int mi = 0; mi < 4; mi++) {
    const int rowg = rowTile * BM + wr * 64 + mi * 16 + fq * 4;
#pragma unroll
    for (int r = 0; r < 4; r++) {
      float p = 0.f;
#pragma unroll
      for (int ni = 0; ni < 4; ni++)
        p += __expf(acc[mi][ni][r] * INVSCALE + biasv[ni]);
#pragma unroll
      for (int m = 1; m < 16; m <<= 1) p += __shfl_xor(p, m);
      if (fr == 0) partials[(size_t)(rowg + r) * pstride + chunk] = p;
    }
  }
}

// ---- per-row: combine chunk partials, selected logits in fp32, loss ----
__global__ __launch_bounds__(256) void rowloss(
    const float* __restrict__ ph, const float* __restrict__ pt1,
    const float* __restrict__ pt2, const int* __restrict__ cidx,
    const float* __restrict__ hiddens, const float* __restrict__ weight,
    const float* __restrict__ bias, const float* __restrict__ tails,
    const float* __restrict__ tail_bias, const int* __restrict__ targets,
    float* __restrict__ losses) {
  const int row = blockIdx.x * 4 + (threadIdx.x >> 6);
  const int lane = threadIdx.x & 63;
  const int t = targets[row];
  const int cl = (t >= SP1) + (t >= SP2);

  float s0 = ph[(size_t)row * PH_STRIDE + lane];  // exactly 64 chunks
  float st = 0.f;
  if (cl == 1) {
    const float* P = pt1 + (size_t)cidx[row] * PT1_STRIDE;
    for (int c = lane; c < PT1_STRIDE; c += 64) st += P[c];
  } else if (cl == 2) {
    const float* P = pt2 + (size_t)cidx[row] * PT2_STRIDE;
    for (int c = lane; c < PT2_STRIDE; c += 64) st += P[c];
  }
#pragma unroll
  for (int m = 1; m < 64; m <<= 1) {
    s0 += __shfl_xor(s0, m);
    st += __shfl_xor(st, m);
  }

  const float* hv = hiddens + (size_t)row * HH;
  const float* w1;
  float b1;
  if (cl == 0) {
    w1 = weight + (size_t)t * HH;
    b1 = bias[t];
  } else if (cl == 1) {
    w1 = tails + HH;  // head col 4001 <-> tail_vectors[1]
    b1 = tail_bias[1];
  } else {
    w1 = tails;       // head col 4000 <-> tail_vectors[0]
    b1 = tail_bias[0];
  }
  float d1 = 0.f, d2 = 0.f;
  for (int i = lane; i < HH; i += 64) d1 += hv[i] * w1[i];
  if (cl > 0) {
    const float* w2 = weight + (size_t)t * HH;
    for (int i = lane; i < HH; i += 64) d2 += hv[i] * w2[i];
  }
#pragma unroll
  for (int m = 1; m < 64; m <<= 1) {
    d1 += __shfl_xor(d1, m);
    d2 += __shfl_xor(d2, m);
  }
  if (lane == 0) {
    float loss = logf(s0) - (d1 + b1);
    if (cl > 0) loss += logf(st) - (d2 + bias[t]);
    losses[row] = loss;
  }
}

__global__ void meanloss(const float* __restrict__ losses, float* __restrict__ out) {
  __shared__ float red[256];
  float s = 0.f;
  for (int i = threadIdx.x; i < NROWS; i += 256) s += losses[i];
  red[threadIdx.x] = s;
  __syncthreads();
  for (int st = 128; st > 0; st >>= 1) {
    if ((int)threadIdx.x < st) red[threadIdx.x] += red[threadIdx.x + st];
    __syncthreads();
  }
  if (threadIdx.x == 0) out[0] = red[0] / (float)NROWS;
}

extern "C" void kernel_launch(void* const* d_in, const int* in_sizes, int n_in,
                              void* d_out, int out_size, void* d_ws, size_t ws_size,
                              hipStream_t stream) {
  const float* weight = (const float*)d_in[0];
  const float* bias = (const float*)d_in[1];
  const float* hiddens = (const float*)d_in[2];
  const float* tails = (const float*)d_in[3];
  const float* tail_bias = (const float*)d_in[4];
  const int* targets = (const int*)d_in[5];
  float* out = (float*)d_out;

  char* ws = (char*)d_ws;
  unsigned char* Wf = (unsigned char*)ws;                      // 50176*1024 = 51,380,224
  unsigned char* Hf = (unsigned char*)(ws + 51380224);         //  4,194,304
  unsigned char* Hc1 = (unsigned char*)(ws + 55574528);        //  4,194,304
  unsigned char* Hc2 = (unsigned char*)(ws + 59768832);        //  4,194,304 (contig w/ Hc1)
  float* ph = (float*)(ws + 63963136);                         //  4096*64*4  = 1,048,576
  float* pt1 = (float*)(ws + 65011712);                        //  4096*250*4 = 4,096,000
  float* pt2 = (float*)(ws + 69107712);                        //  4096*470*4 = 7,700,480
  float* biasr = (float*)(ws + 76808192);                      //  50176*4    = 200,704
  int* cidx = (int*)(ws + 77008896);                           //  16,384
  int* counts = (int*)(ws + 77025280);                         //  64
  float* losses = (float*)(ws + 77025344);                     //  16,384

  hipLaunchKernelGGL(convW, dim3(2048), dim3(256), 0, stream, weight, tails, Wf);
  hipLaunchKernelGGL(biasK, dim3((VPAD + 255) / 256), dim3(256), 0, stream, bias,
                     tail_bias, biasr);
  hipLaunchKernelGGL(convH, dim3(512), dim3(256), 0, stream, hiddens, Hf);
  hipLaunchKernelGGL(scanK, dim3(1), dim3(1024), 0, stream, targets, cidx, counts);
  hipLaunchKernelGGL(zeroHc, dim3(1024), dim3(256), 0, stream, (uint4*)Hc1);
  hipLaunchKernelGGL(gatherK, dim3(NROWS / 4), dim3(256), 0, stream, Hf, targets, cidx,
                     Hc1, Hc2);
  // head: all rows x cols [0,4002) (padded to 4096)
  hipLaunchKernelGGL(gemm_lse, dim3(16 * CT_HEAD), dim3(512), 0, stream, Hf, Wf,
                     CT_HEAD, 0, CL_HEAD, biasr, ph, counts, 2);
  // tail1: cluster-1 rows x cols [4002,20002)
  hipLaunchKernelGGL(gemm_lse, dim3(16 * CT_T1), dim3(512), 0, stream, Hc1, Wf, CT_T1,
                     CB_T1, CL_T1, biasr, pt1, counts, 0);
  // tail2: cluster-2 rows x cols [20002,50002) (padded to 30080)
  hipLaunchKernelGGL(gemm_lse, dim3(16 * CT_T2), dim3(512), 0, stream, Hc2, Wf, CT_T2,
                     CB_T2, CL_T2, biasr, pt2, counts, 1);
  hipLaunchKernelGGL(rowloss, dim3(NROWS / 4), dim3(256), 0, stream, ph, pt1, pt2, cidx,
                     hiddens, weight, bias, tails, tail_bias, targets, losses);
  hipLaunchKernelGGL(meanloss, dim3(1), dim3(256), 0, stream, losses, out);
}

// Round 9
// 288.820 us; speedup vs baseline: 4.3213x; 4.3213x over previous
//
#include <hip/hip_runtime.h>
#include <hip/hip_bf16.h>
#include <cstdint>
#include <cstddef>

#define VV 50000
#define HH 1024
#define NROWS 4096
#define VPAD 50176      // padded reordered-W rows
#define SP1 4000
#define SP2 20000
#define SP3 50000

#define BM 256
#define BN 128
#define BK 128
#define NKT (HH / BK)           // 8
#define A_SLOT_B (BM * BK)      // 32768 bytes (fp8)
#define B_SLOT_B (BN * BK)      // 16384 bytes
#define SLOT_B (A_SLOT_B + B_SLOT_B)  // 49152 B/slot, 3 slots = 144 KiB

// reordered-W column map: [0..3999]=weight, [4000..4001]=tail_vectors,
// [4002..50001]=weight[4000..49999], rest zero-pad
#define CB_T1 4002
#define CB_T2 20002
#define CL_HEAD 4002
#define CL_T1 20002
#define CL_T2 50002
#define CT_HEAD 32
#define CT_T1 125
#define CT_T2 235
#define PH_STRIDE 64    // 2*CT_HEAD
#define PT1_STRIDE 250  // 2*CT_T1
#define PT2_STRIDE 470  // 2*CT_T2

#define WSCALE 256.0f
#define HSCALE 16.0f
#define INVSCALE (1.0f / 4096.0f)
#define UNIT_SCALE 0x7f7f7f7fu  // E8M0 1.0 in every byte

typedef __attribute__((ext_vector_type(4))) int i32x4;
typedef __attribute__((ext_vector_type(8))) int i32x8;
typedef __attribute__((ext_vector_type(4))) float f32x4;

typedef __attribute__((address_space(1))) unsigned int uint_g;
typedef __attribute__((address_space(3))) unsigned int uint_l;

__device__ __forceinline__ void gload16(const void* g, void* l) {
  __builtin_amdgcn_global_load_lds((const uint_g*)g, (uint_l*)l, 16, 0, 0);
}

// pack 4 floats -> 4 fp8 e4m3 bytes
__device__ __forceinline__ unsigned int pk4(float a, float b, float c, float d) {
  int p = __builtin_amdgcn_cvt_pk_fp8_f32(a, b, 0, 0);
  p = __builtin_amdgcn_cvt_pk_fp8_f32(c, d, p, 1);
  return (unsigned int)p;
}

// ---- convert weight + tail_vectors -> fp8 (x256), reordered rows ----
__global__ void convW(const float* __restrict__ w, const float* __restrict__ tails,
                      unsigned char* __restrict__ Wf) {
  const size_t nq = (size_t)VPAD * HH / 4;
  for (size_t q = (size_t)blockIdx.x * blockDim.x + threadIdx.x; q < nq;
       q += (size_t)gridDim.x * blockDim.x) {
    const size_t e = q * 4;
    const int row = (int)(e >> 10);
    unsigned int o;
    if (row < 4000) {
      float4 f = *(const float4*)(w + e);
      o = pk4(f.x * WSCALE, f.y * WSCALE, f.z * WSCALE, f.w * WSCALE);
    } else if (row < 4002) {
      float4 f = *(const float4*)(tails + (e - (size_t)4000 * HH));
      o = pk4(f.x * WSCALE, f.y * WSCALE, f.z * WSCALE, f.w * WSCALE);
    } else if (row < 50002) {
      float4 f = *(const float4*)(w + (e - 2048));
      o = pk4(f.x * WSCALE, f.y * WSCALE, f.z * WSCALE, f.w * WSCALE);
    } else {
      o = 0u;
    }
    *(unsigned int*)(Wf + e) = o;
  }
}

// reordered bias (pads get -1e30 so exp() underflows to 0)
__global__ void biasK(const float* __restrict__ bias, const float* __restrict__ tb,
                      float* __restrict__ biasr) {
  const int r = blockIdx.x * 256 + threadIdx.x;
  if (r >= VPAD) return;
  float v;
  if (r < 4000) v = bias[r];
  else if (r == 4000) v = tb[0];
  else if (r == 4001) v = tb[1];
  else if (r < 50002) v = bias[r - 2];
  else v = -1e30f;
  biasr[r] = v;
}

__global__ void convH(const float* __restrict__ h, unsigned char* __restrict__ Hf) {
  const size_t nq = (size_t)NROWS * HH / 4;
  for (size_t q = (size_t)blockIdx.x * blockDim.x + threadIdx.x; q < nq;
       q += (size_t)gridDim.x * blockDim.x) {
    const size_t e = q * 4;
    float4 f = *(const float4*)(h + e);
    *(unsigned int*)(Hf + e) =
        pk4(f.x * HSCALE, f.y * HSCALE, f.z * HSCALE, f.w * HSCALE);
  }
}

// ---- deterministic cluster scan: compact index per row, counts ----
__global__ __launch_bounds__(1024) void scanK(const int* __restrict__ targets,
                                              int* __restrict__ cidx,
                                              int* __restrict__ counts) {
  __shared__ int s1[1024], s2[1024];
  const int tid = threadIdx.x;
  int c[4];
  int n1 = 0, n2 = 0;
#pragma unroll
  for (int j = 0; j < 4; j++) {
    const int t = targets[tid * 4 + j];
    c[j] = (t >= SP1) + (t >= SP2);
    n1 += (c[j] == 1);
    n2 += (c[j] == 2);
  }
  s1[tid] = n1;
  s2[tid] = n2;
  __syncthreads();
  for (int off = 1; off < 1024; off <<= 1) {
    const int a1 = (tid >= off) ? s1[tid - off] : 0;
    const int a2 = (tid >= off) ? s2[tid - off] : 0;
    __syncthreads();
    s1[tid] += a1;
    s2[tid] += a2;
    __syncthreads();
  }
  int e1 = s1[tid] - n1, e2 = s2[tid] - n2;
#pragma unroll
  for (int j = 0; j < 4; j++) {
    if (c[j] == 1) cidx[tid * 4 + j] = e1++;
    else if (c[j] == 2) cidx[tid * 4 + j] = e2++;
    else cidx[tid * 4 + j] = 0;
  }
  if (tid == 1023) {
    counts[0] = s1[1023];
    counts[1] = s2[1023];
    counts[2] = NROWS;
  }
}

// zero both compact-H fp8 buffers (contiguous)
__global__ void zeroHc(uint4* __restrict__ Hc) {
  const size_t n16 = (size_t)2 * NROWS * HH / 16;
  const uint4 z = {0u, 0u, 0u, 0u};
  for (size_t i = (size_t)blockIdx.x * blockDim.x + threadIdx.x; i < n16;
       i += (size_t)gridDim.x * blockDim.x)
    Hc[i] = z;
}

// gather fp8 H rows into per-cluster compact matrices (1 wave per row)
__global__ __launch_bounds__(256) void gatherK(const unsigned char* __restrict__ Hf,
                                               const int* __restrict__ targets,
                                               const int* __restrict__ cidx,
                                               unsigned char* __restrict__ Hc1,
                                               unsigned char* __restrict__ Hc2) {
  const int row = blockIdx.x * 4 + (threadIdx.x >> 6);
  const int lane = threadIdx.x & 63;
  const int t = targets[row];
  const int cl = (t >= SP1) + (t >= SP2);
  if (cl == 0) return;
  unsigned char* dst = (cl == 1 ? Hc1 : Hc2) + (size_t)cidx[row] * HH;
  const unsigned char* src = Hf + (size_t)row * HH;
  *(uint4*)(dst + lane * 16) = *(const uint4*)(src + lane * 16);
}

// ---- MX-fp8 GEMM (unit scales) + single-segment sum-exp epilogue ----
// 1-D grid, colTile fastest, trailing early-exit (XCD-balanced).
// 512 threads (8 waves = 4M x 2N, wave 64x64); BK=128, 3-slot LDS ring
// (144 KiB -> 1 block/CU -> 2 waves/SIMD; __launch_bounds__(512,2)).
// distance-2 prefetch, counted vmcnt(6), XOR-swizzle (R&7)<<4.
// K-loop is #pragma unroll 1: full unroll extended all 8 tiles' fragment
// live ranges -> scratch spill (rounds 7-8: 2.9 GB/dispatch scratch).
__global__ __launch_bounds__(512, 2) void gemm_lse(
    const unsigned char* __restrict__ Ab, const unsigned char* __restrict__ Wf,
    int CT, int colbase, int col_limit, const float* __restrict__ biasr,
    float* __restrict__ partials, const int* __restrict__ Mptr, int mslot) {
  const int Mc = Mptr[mslot];
  const int bid = blockIdx.x;
  const int rowTile = bid / CT;
  const int colTile = bid - rowTile * CT;
  if (rowTile * BM >= Mc) return;

  __shared__ __align__(16) unsigned char lds[3 * SLOT_B];  // 147456 B

  const int tid = threadIdx.x;
  const int w = tid >> 6, lane = tid & 63;
  const int wr = w >> 1, wc = w & 1;
  const int fr = lane & 15, fq = lane >> 4;
  const unsigned char* Ag = Ab + (size_t)rowTile * BM * HH;
  const unsigned char* Bg = Wf + (size_t)(colbase + colTile * BN) * HH;

  // staging source offsets (bytes): linear LDS dest chunk c -> (R=c>>3, j=c&7),
  // global byte = R*HH + k0 + ((j*16) ^ ((R&7)<<4))
  int srcA[4], srcB[2];
#pragma unroll
  for (int i = 0; i < 4; i++) {
    const int c = i * 512 + tid;
    const int R = c >> 3, j = c & 7;
    srcA[i] = R * HH + ((j * 16) ^ ((R & 7) << 4));
  }
#pragma unroll
  for (int i = 0; i < 2; i++) {
    const int c = i * 512 + tid;
    const int R = c >> 3, j = c & 7;
    srcB[i] = R * HH + ((j * 16) ^ ((R & 7) << 4));
  }

  // fragment read offsets (bytes within slot); h=1 read is off ^ 16
  // (bit-4 flip commutes with the XOR swizzle)
  int offA[4], offB[4];
#pragma unroll
  for (int mi = 0; mi < 4; mi++) {
    const int R = wr * 64 + mi * 16 + fr;
    offA[mi] = R * BK + ((fq * 32) ^ ((R & 7) << 4));
  }
#pragma unroll
  for (int ni = 0; ni < 4; ni++) {
    const int R = wc * 64 + ni * 16 + fr;
    offB[ni] = R * BK + ((fq * 32) ^ ((R & 7) << 4));
  }

  f32x4 acc[4][4];
#pragma unroll
  for (int i = 0; i < 4; i++)
#pragma unroll
    for (int j = 0; j < 4; j++) acc[i][j] = (f32x4){0.f, 0.f, 0.f, 0.f};

  auto STAGE = [&](int t) {
    const int slot = t % 3;
    unsigned char* Asl = lds + slot * SLOT_B;
    unsigned char* Bsl = Asl + A_SLOT_B;
    const int k0 = t * BK;  // byte offset (1 B/elem)
#pragma unroll
    for (int i = 0; i < 4; i++)
      gload16(Ag + (size_t)srcA[i] + k0, Asl + (i * 512 + tid) * 16);
#pragma unroll
    for (int i = 0; i < 2; i++)
      gload16(Bg + (size_t)srcB[i] + k0, Bsl + (i * 512 + tid) * 16);
  };

  STAGE(0);
  STAGE(1);

#pragma unroll 1
  for (int t = 0; t < NKT; ++t) {
    if (t < NKT - 1)
      asm volatile("s_waitcnt vmcnt(6)" ::: "memory");
    else
      asm volatile("s_waitcnt vmcnt(0)" ::: "memory");
    __builtin_amdgcn_s_barrier();
    if (t + 2 < NKT) STAGE(t + 2);

    const unsigned char* Asl = lds + (t % 3) * SLOT_B;
    const unsigned char* Bsl = Asl + A_SLOT_B;
    // B fragments for the whole tile (32 VGPR)
    i32x8 b8[4];
#pragma unroll
    for (int ni = 0; ni < 4; ni++) {
      i32x4 lo = *(const i32x4*)(Bsl + offB[ni]);
      i32x4 hi = *(const i32x4*)(Bsl + (offB[ni] ^ 16));
      b8[ni] = __builtin_shufflevector(lo, hi, 0, 1, 2, 3, 4, 5, 6, 7);
    }
    __builtin_amdgcn_s_setprio(1);
#pragma unroll
    for (int mi = 0; mi < 4; mi++) {
      // stream one A fragment (8 VGPR) through 4 MFMAs
      i32x4 lo = *(const i32x4*)(Asl + offA[mi]);
      i32x4 hi = *(const i32x4*)(Asl + (offA[mi] ^ 16));
      i32x8 a8 = __builtin_shufflevector(lo, hi, 0, 1, 2, 3, 4, 5, 6, 7);
#pragma unroll
      for (int ni = 0; ni < 4; ni++)
        acc[mi][ni] = __builtin_amdgcn_mfma_scale_f32_16x16x128_f8f6f4(
            a8, b8[ni], acc[mi][ni], 0, 0, 0, UNIT_SCALE, 0, UNIT_SCALE);
    }
    __builtin_amdgcn_s_setprio(0);
    __builtin_amdgcn_s_barrier();
  }

  // ---- epilogue: per-(row, 64-col chunk) sum of exp(logit/4096 + bias) ----
  const int colw = colTile * BN + wc * 64;
  float biasv[4];
#pragma unroll
  for (int ni = 0; ni < 4; ni++) {
    const int gcol = colbase + colw + ni * 16 + fr;
    biasv[ni] = (gcol < col_limit) ? biasr[gcol] : -1e30f;
  }
  const int chunk = colTile * 2 + wc;
  const int pstride = CT * 2;

#pragma unroll
  for (int mi = 0; mi < 4; mi++) {
    const int rowg = rowTile * BM + wr * 64 + mi * 16 + fq * 4;
#pragma unroll
    for (int r = 0; r < 4; r++) {
      float p = 0.f;
#pragma unroll
      for (int ni = 0; ni < 4; ni++)
        p += __expf(acc[mi][ni][r] * INVSCALE + biasv[ni]);
#pragma unroll
      for (int m = 1; m < 16; m <<= 1) p += __shfl_xor(p, m);
      if (fr == 0) partials[(size_t)(rowg + r) * pstride + chunk] = p;
    }
  }
}

// ---- per-row: combine chunk partials, selected logits in fp32, loss ----
__global__ __launch_bounds__(256) void rowloss(
    const float* __restrict__ ph, const float* __restrict__ pt1,
    const float* __restrict__ pt2, const int* __restrict__ cidx,
    const float* __restrict__ hiddens, const float* __restrict__ weight,
    const float* __restrict__ bias, const float* __restrict__ tails,
    const float* __restrict__ tail_bias, const int* __restrict__ targets,
    float* __restrict__ losses) {
  const int row = blockIdx.x * 4 + (threadIdx.x >> 6);
  const int lane = threadIdx.x & 63;
  const int t = targets[row];
  const int cl = (t >= SP1) + (t >= SP2);

  float s0 = ph[(size_t)row * PH_STRIDE + lane];  // exactly 64 chunks
  float st = 0.f;
  if (cl == 1) {
    const float* P = pt1 + (size_t)cidx[row] * PT1_STRIDE;
    for (int c = lane; c < PT1_STRIDE; c += 64) st += P[c];
  } else if (cl == 2) {
    const float* P = pt2 + (size_t)cidx[row] * PT2_STRIDE;
    for (int c = lane; c < PT2_STRIDE; c += 64) st += P[c];
  }
#pragma unroll
  for (int m = 1; m < 64; m <<= 1) {
    s0 += __shfl_xor(s0, m);
    st += __shfl_xor(st, m);
  }

  const float* hv = hiddens + (size_t)row * HH;
  const float* w1;
  float b1;
  if (cl == 0) {
    w1 = weight + (size_t)t * HH;
    b1 = bias[t];
  } else if (cl == 1) {
    w1 = tails + HH;  // head col 4001 <-> tail_vectors[1]
    b1 = tail_bias[1];
  } else {
    w1 = tails;       // head col 4000 <-> tail_vectors[0]
    b1 = tail_bias[0];
  }
  float d1 = 0.f, d2 = 0.f;
  for (int i = lane; i < HH; i += 64) d1 += hv[i] * w1[i];
  if (cl > 0) {
    const float* w2 = weight + (size_t)t * HH;
    for (int i = lane; i < HH; i += 64) d2 += hv[i] * w2[i];
  }
#pragma unroll
  for (int m = 1; m < 64; m <<= 1) {
    d1 += __shfl_xor(d1, m);
    d2 += __shfl_xor(d2, m);
  }
  if (lane == 0) {
    float loss = logf(s0) - (d1 + b1);
    if (cl > 0) loss += logf(st) - (d2 + bias[t]);
    losses[row] = loss;
  }
}

__global__ void meanloss(const float* __restrict__ losses, float* __restrict__ out) {
  __shared__ float red[256];
  float s = 0.f;
  for (int i = threadIdx.x; i < NROWS; i += 256) s += losses[i];
  red[threadIdx.x] = s;
  __syncthreads();
  for (int st = 128; st > 0; st >>= 1) {
    if ((int)threadIdx.x < st) red[threadIdx.x] += red[threadIdx.x + st];
    __syncthreads();
  }
  if (threadIdx.x == 0) out[0] = red[0] / (float)NROWS;
}

extern "C" void kernel_launch(void* const* d_in, const int* in_sizes, int n_in,
                              void* d_out, int out_size, void* d_ws, size_t ws_size,
                              hipStream_t stream) {
  const float* weight = (const float*)d_in[0];
  const float* bias = (const float*)d_in[1];
  const float* hiddens = (const float*)d_in[2];
  const float* tails = (const float*)d_in[3];
  const float* tail_bias = (const float*)d_in[4];
  const int* targets = (const int*)d_in[5];
  float* out = (float*)d_out;

  char* ws = (char*)d_ws;
  unsigned char* Wf = (unsigned char*)ws;                      // 50176*1024 = 51,380,224
  unsigned char* Hf = (unsigned char*)(ws + 51380224);         //  4,194,304
  unsigned char* Hc1 = (unsigned char*)(ws + 55574528);        //  4,194,304
  unsigned char* Hc2 = (unsigned char*)(ws + 59768832);        //  4,194,304 (contig w/ Hc1)
  float* ph = (float*)(ws + 63963136);                         //  4096*64*4  = 1,048,576
  float* pt1 = (float*)(ws + 65011712);                        //  4096*250*4 = 4,096,000
  float* pt2 = (float*)(ws + 69107712);                        //  4096*470*4 = 7,700,480
  float* biasr = (float*)(ws + 76808192);                      //  50176*4    = 200,704
  int* cidx = (int*)(ws + 77008896);                           //  16,384
  int* counts = (int*)(ws + 77025280);                         //  64
  float* losses = (float*)(ws + 77025344);                     //  16,384

  hipLaunchKernelGGL(convW, dim3(2048), dim3(256), 0, stream, weight, tails, Wf);
  hipLaunchKernelGGL(biasK, dim3((VPAD + 255) / 256), dim3(256), 0, stream, bias,
                     tail_bias, biasr);
  hipLaunchKernelGGL(convH, dim3(512), dim3(256), 0, stream, hiddens, Hf);
  hipLaunchKernelGGL(scanK, dim3(1), dim3(1024), 0, stream, targets, cidx, counts);
  hipLaunchKernelGGL(zeroHc, dim3(1024), dim3(256), 0, stream, (uint4*)Hc1);
  hipLaunchKernelGGL(gatherK, dim3(NROWS / 4), dim3(256), 0, stream, Hf, targets, cidx,
                     Hc1, Hc2);
  // head: all rows x cols [0,4002) (padded to 4096)
  hipLaunchKernelGGL(gemm_lse, dim3(16 * CT_HEAD), dim3(512), 0, stream, Hf, Wf,
                     CT_HEAD, 0, CL_HEAD, biasr, ph, counts, 2);
  // tail1: cluster-1 rows x cols [4002,20002)
  hipLaunchKernelGGL(gemm_lse, dim3(16 * CT_T1), dim3(512), 0, stream, Hc1, Wf, CT_T1,
                     CB_T1, CL_T1, biasr, pt1, counts, 0);
  // tail2: cluster-2 rows x cols [20002,50002) (padded to 30080)
  hipLaunchKernelGGL(gemm_lse, dim3(16 * CT_T2), dim3(512), 0, stream, Hc2, Wf, CT_T2,
                     CB_T2, CL_T2, biasr, pt2, counts, 1);
  hipLaunchKernelGGL(rowloss, dim3(NROWS / 4), dim3(256), 0, stream, ph, pt1, pt2, cidx,
                     hiddens, weight, bias, tails, tail_bias, targets, losses);
  hipLaunchKernelGGL(meanloss, dim3(1), dim3(256), 0, stream, losses, out);
}

// Round 10
// 279.303 us; speedup vs baseline: 4.4686x; 1.0341x over previous
//
#include <hip/hip_runtime.h>
#include <hip/hip_bf16.h>
#include <cstdint>
#include <cstddef>

#define VV 50000
#define HH 1024
#define NROWS 4096
#define VPAD 50176      // padded reordered-W rows
#define SP1 4000
#define SP2 20000
#define SP3 50000

#define BM 128
#define BN 128
#define BK 128
#define NKT (HH / BK)           // 8
#define ROWB 144                // LDS row stride: 128 data + 16 pad (bank rotate)
#define A_SLOT_B (BM * ROWB)    // 18432
#define SLOT_B (2 * A_SLOT_B)   // 36864 B/slot; 2 slots = 73728 B -> 2 blocks/CU
#define NCH (SLOT_B / 16)       // 2304 chunks per tile
#define LPT (NCH / 256)         // 9 loads per thread per tile

// reordered-W column map: [0..3999]=weight, [4000..4001]=tail_vectors,
// [4002..50001]=weight[4000..49999], rest zero-pad
#define CB_T1 4002
#define CB_T2 20002
#define CL_HEAD 4002
#define CL_T1 20002
#define CL_T2 50002
#define CT_HEAD 32
#define CT_T1 125
#define CT_T2 235
#define PH_STRIDE 64    // 2*CT_HEAD
#define PT1_STRIDE 250  // 2*CT_T1
#define PT2_STRIDE 470  // 2*CT_T2
#define NRT 32          // row tiles (4096/128)

#define WSCALE 256.0f
#define HSCALE 16.0f
#define INVSCALE (1.0f / 4096.0f)
#define UNIT_SCALE 0x7f7f7f7fu  // E8M0 1.0 in every byte

typedef __attribute__((ext_vector_type(4))) int i32x4;
typedef __attribute__((ext_vector_type(8))) int i32x8;
typedef __attribute__((ext_vector_type(4))) float f32x4;

typedef __attribute__((address_space(1))) unsigned int uint_g;
typedef __attribute__((address_space(3))) unsigned int uint_l;

__device__ __forceinline__ void gload16(const void* g, void* l) {
  __builtin_amdgcn_global_load_lds((const uint_g*)g, (uint_l*)l, 16, 0, 0);
}

// pack 4 floats -> 4 fp8 e4m3 bytes
__device__ __forceinline__ unsigned int pk4(float a, float b, float c, float d) {
  int p = __builtin_amdgcn_cvt_pk_fp8_f32(a, b, 0, 0);
  p = __builtin_amdgcn_cvt_pk_fp8_f32(c, d, p, 1);
  return (unsigned int)p;
}

// ---- convert weight + tail_vectors -> fp8 (x256), reordered rows ----
__global__ void convW(const float* __restrict__ w, const float* __restrict__ tails,
                      unsigned char* __restrict__ Wf) {
  const size_t nq = (size_t)VPAD * HH / 4;
  for (size_t q = (size_t)blockIdx.x * blockDim.x + threadIdx.x; q < nq;
       q += (size_t)gridDim.x * blockDim.x) {
    const size_t e = q * 4;
    const int row = (int)(e >> 10);
    unsigned int o;
    if (row < 4000) {
      float4 f = *(const float4*)(w + e);
      o = pk4(f.x * WSCALE, f.y * WSCALE, f.z * WSCALE, f.w * WSCALE);
    } else if (row < 4002) {
      float4 f = *(const float4*)(tails + (e - (size_t)4000 * HH));
      o = pk4(f.x * WSCALE, f.y * WSCALE, f.z * WSCALE, f.w * WSCALE);
    } else if (row < 50002) {
      float4 f = *(const float4*)(w + (e - 2048));
      o = pk4(f.x * WSCALE, f.y * WSCALE, f.z * WSCALE, f.w * WSCALE);
    } else {
      o = 0u;
    }
    *(unsigned int*)(Wf + e) = o;
  }
}

// reordered bias (pads get -1e30 so exp() underflows to 0)
__global__ void biasK(const float* __restrict__ bias, const float* __restrict__ tb,
                      float* __restrict__ biasr) {
  const int r = blockIdx.x * 256 + threadIdx.x;
  if (r >= VPAD) return;
  float v;
  if (r < 4000) v = bias[r];
  else if (r == 4000) v = tb[0];
  else if (r == 4001) v = tb[1];
  else if (r < 50002) v = bias[r - 2];
  else v = -1e30f;
  biasr[r] = v;
}

__global__ void convH(const float* __restrict__ h, unsigned char* __restrict__ Hf) {
  const size_t nq = (size_t)NROWS * HH / 4;
  for (size_t q = (size_t)blockIdx.x * blockDim.x + threadIdx.x; q < nq;
       q += (size_t)gridDim.x * blockDim.x) {
    const size_t e = q * 4;
    float4 f = *(const float4*)(h + e);
    *(unsigned int*)(Hf + e) =
        pk4(f.x * HSCALE, f.y * HSCALE, f.z * HSCALE, f.w * HSCALE);
  }
}

// ---- deterministic cluster scan: compact index per row, counts ----
__global__ __launch_bounds__(1024) void scanK(const int* __restrict__ targets,
                                              int* __restrict__ cidx,
                                              int* __restrict__ counts) {
  __shared__ int s1[1024], s2[1024];
  const int tid = threadIdx.x;
  int c[4];
  int n1 = 0, n2 = 0;
#pragma unroll
  for (int j = 0; j < 4; j++) {
    const int t = targets[tid * 4 + j];
    c[j] = (t >= SP1) + (t >= SP2);
    n1 += (c[j] == 1);
    n2 += (c[j] == 2);
  }
  s1[tid] = n1;
  s2[tid] = n2;
  __syncthreads();
  for (int off = 1; off < 1024; off <<= 1) {
    const int a1 = (tid >= off) ? s1[tid - off] : 0;
    const int a2 = (tid >= off) ? s2[tid - off] : 0;
    __syncthreads();
    s1[tid] += a1;
    s2[tid] += a2;
    __syncthreads();
  }
  int e1 = s1[tid] - n1, e2 = s2[tid] - n2;
#pragma unroll
  for (int j = 0; j < 4; j++) {
    if (c[j] == 1) cidx[tid * 4 + j] = e1++;
    else if (c[j] == 2) cidx[tid * 4 + j] = e2++;
    else cidx[tid * 4 + j] = 0;
  }
  if (tid == 1023) {
    counts[0] = s1[1023];
    counts[1] = s2[1023];
    counts[2] = NROWS;
  }
}

// zero both compact-H fp8 buffers (contiguous)
__global__ void zeroHc(uint4* __restrict__ Hc) {
  const size_t n16 = (size_t)2 * NROWS * HH / 16;
  const uint4 z = {0u, 0u, 0u, 0u};
  for (size_t i = (size_t)blockIdx.x * blockDim.x + threadIdx.x; i < n16;
       i += (size_t)gridDim.x * blockDim.x)
    Hc[i] = z;
}

// gather fp8 H rows into per-cluster compact matrices (1 wave per row)
__global__ __launch_bounds__(256) void gatherK(const unsigned char* __restrict__ Hf,
                                               const int* __restrict__ targets,
                                               const int* __restrict__ cidx,
                                               unsigned char* __restrict__ Hc1,
                                               unsigned char* __restrict__ Hc2) {
  const int row = blockIdx.x * 4 + (threadIdx.x >> 6);
  const int lane = threadIdx.x & 63;
  const int t = targets[row];
  const int cl = (t >= SP1) + (t >= SP2);
  if (cl == 0) return;
  unsigned char* dst = (cl == 1 ? Hc1 : Hc2) + (size_t)cidx[row] * HH;
  const unsigned char* src = Hf + (size_t)row * HH;
  *(uint4*)(dst + lane * 16) = *(const uint4*)(src + lane * 16);
}

// ---- MX-fp8 GEMM (unit scales) + single-segment sum-exp epilogue ----
// 1-D grid, colTile fastest, trailing early-exit (XCD-balanced).
// 256 threads (4 waves = 2M x 2N, wave 64x64); BK=128, 2-slot double buffer.
// LDS rows padded to 144 B (bank rotation, classic +pad fix -> 0 conflicts);
// pad is gload_lds-compatible: 9 chunks/row, chunk 8 stages a dup (never read).
// 72 KiB LDS -> 2 independent blocks/CU (cross-block MFMA/LDS overlap, m114).
// Counted vmcnt(9); K-loop #pragma unroll 1 (full unroll spilled, r7/r8).
__global__ __launch_bounds__(256, 2) void gemm_lse(
    const unsigned char* __restrict__ Ab, const unsigned char* __restrict__ Wf,
    int CT, int colbase, int col_limit, const float* __restrict__ biasr,
    float* __restrict__ partials, const int* __restrict__ Mptr, int mslot) {
  const int Mc = Mptr[mslot];
  const int bid = blockIdx.x;
  const int rowTile = bid / CT;
  const int colTile = bid - rowTile * CT;
  if (rowTile * BM >= Mc) return;

  __shared__ __align__(16) unsigned char lds[2 * SLOT_B];  // 73728 B

  const int tid = threadIdx.x;
  const int w = tid >> 6, lane = tid & 63;
  const int wr = w >> 1, wc = w & 1;
  const int fr = lane & 15, fq = lane >> 4;
  const unsigned char* Ag = Ab + (size_t)rowTile * BM * HH;
  const unsigned char* Bg = Wf + (size_t)(colbase + colTile * BN) * HH;

  // staging: chunk c (16B) -> dest byte c*16; source precomputed per i.
  // A: c in [0,1152): row=c/9, j=c%9 ; B: c-1152 likewise. j==8 -> dup of j=0.
  const unsigned char* srcPtr[LPT];
#pragma unroll
  for (int i = 0; i < LPT; i++) {
    const int c = i * 256 + tid;
    const bool isA = c < NCH / 2;
    const int cc = isA ? c : c - NCH / 2;
    const int row = cc / 9;
    const int j = cc - row * 9;
    const int jb = (j < 8) ? j * 16 : 0;
    srcPtr[i] = (isA ? Ag : Bg) + (size_t)row * HH + jb;
  }

  // fragment read offsets (bytes within slot); hi half at +16 (contiguous)
  int offA[4], offB[4];
#pragma unroll
  for (int mi = 0; mi < 4; mi++) {
    const int R = wr * 64 + mi * 16 + fr;
    offA[mi] = R * ROWB + fq * 32;
  }
#pragma unroll
  for (int ni = 0; ni < 4; ni++) {
    const int R = wc * 64 + ni * 16 + fr;
    offB[ni] = A_SLOT_B + R * ROWB + fq * 32;
  }

  f32x4 acc[4][4];
#pragma unroll
  for (int i = 0; i < 4; i++)
#pragma unroll
    for (int j = 0; j < 4; j++) acc[i][j] = (f32x4){0.f, 0.f, 0.f, 0.f};

  auto STAGE = [&](int t) {
    unsigned char* base = lds + (t & 1) * SLOT_B;
    const int k0 = t * BK;  // byte offset (1 B/elem)
#pragma unroll
    for (int i = 0; i < LPT; i++)
      gload16(srcPtr[i] + k0, base + (i * 256 + tid) * 16);
  };

  STAGE(0);

#pragma unroll 1
  for (int t = 0; t < NKT; ++t) {
    if (t + 1 < NKT) {
      STAGE(t + 1);
      asm volatile("s_waitcnt vmcnt(9)" ::: "memory");
    } else {
      asm volatile("s_waitcnt vmcnt(0)" ::: "memory");
    }
    __builtin_amdgcn_s_barrier();

    const unsigned char* sl = lds + (t & 1) * SLOT_B;
    // B fragments for the whole tile (32 VGPR)
    i32x8 b8[4];
#pragma unroll
    for (int ni = 0; ni < 4; ni++) {
      i32x4 lo = *(const i32x4*)(sl + offB[ni]);
      i32x4 hi = *(const i32x4*)(sl + offB[ni] + 16);
      b8[ni] = __builtin_shufflevector(lo, hi, 0, 1, 2, 3, 4, 5, 6, 7);
    }
    __builtin_amdgcn_s_setprio(1);
#pragma unroll
    for (int mi = 0; mi < 4; mi++) {
      i32x4 lo = *(const i32x4*)(sl + offA[mi]);
      i32x4 hi = *(const i32x4*)(sl + offA[mi] + 16);
      i32x8 a8 = __builtin_shufflevector(lo, hi, 0, 1, 2, 3, 4, 5, 6, 7);
#pragma unroll
      for (int ni = 0; ni < 4; ni++)
        acc[mi][ni] = __builtin_amdgcn_mfma_scale_f32_16x16x128_f8f6f4(
            a8, b8[ni], acc[mi][ni], 0, 0, 0, UNIT_SCALE, 0, UNIT_SCALE);
    }
    __builtin_amdgcn_s_setprio(0);
    __builtin_amdgcn_s_barrier();
  }

  // ---- epilogue: per-(row, 64-col chunk) sum of exp(logit/4096 + bias) ----
  const int colw = colTile * BN + wc * 64;
  float biasv[4];
#pragma unroll
  for (int ni = 0; ni < 4; ni++) {
    const int gcol = colbase + colw + ni * 16 + fr;
    biasv[ni] = (gcol < col_limit) ? biasr[gcol] : -1e30f;
  }
  const int chunk = colTile * 2 + wc;
  const int pstride = CT * 2;

#pragma unroll
  for (int mi = 0; mi < 4; mi++) {
    const int rowg = rowTile * BM + wr * 64 + mi * 16 + fq * 4;
#pragma unroll
    for (int r = 0; r < 4; r++) {
      float p = 0.f;
#pragma unroll
      for (int ni = 0; ni < 4; ni++)
        p += __expf(acc[mi][ni][r] * INVSCALE + biasv[ni]);
#pragma unroll
      for (int m = 1; m < 16; m <<= 1) p += __shfl_xor(p, m);
      if (fr == 0) partials[(size_t)(rowg + r) * pstride + chunk] = p;
    }
  }
}

// ---- per-row: combine chunk partials, selected logits in fp32, loss ----
__global__ __launch_bounds__(256) void rowloss(
    const float* __restrict__ ph, const float* __restrict__ pt1,
    const float* __restrict__ pt2, const int* __restrict__ cidx,
    const float* __restrict__ hiddens, const float* __restrict__ weight,
    const float* __restrict__ bias, const float* __restrict__ tails,
    const float* __restrict__ tail_bias, const int* __restrict__ targets,
    float* __restrict__ losses) {
  const int row = blockIdx.x * 4 + (threadIdx.x >> 6);
  const int lane = threadIdx.x & 63;
  const int t = targets[row];
  const int cl = (t >= SP1) + (t >= SP2);

  float s0 = ph[(size_t)row * PH_STRIDE + lane];  // exactly 64 chunks
  float st = 0.f;
  if (cl == 1) {
    const float* P = pt1 + (size_t)cidx[row] * PT1_STRIDE;
    for (int c = lane; c < PT1_STRIDE; c += 64) st += P[c];
  } else if (cl == 2) {
    const float* P = pt2 + (size_t)cidx[row] * PT2_STRIDE;
    for (int c = lane; c < PT2_STRIDE; c += 64) st += P[c];
  }
#pragma unroll
  for (int m = 1; m < 64; m <<= 1) {
    s0 += __shfl_xor(s0, m);
    st += __shfl_xor(st, m);
  }

  const float* hv = hiddens + (size_t)row * HH;
  const float* w1;
  float b1;
  if (cl == 0) {
    w1 = weight + (size_t)t * HH;
    b1 = bias[t];
  } else if (cl == 1) {
    w1 = tails + HH;  // head col 4001 <-> tail_vectors[1]
    b1 = tail_bias[1];
  } else {
    w1 = tails;       // head col 4000 <-> tail_vectors[0]
    b1 = tail_bias[0];
  }
  float d1 = 0.f, d2 = 0.f;
  for (int i = lane; i < HH; i += 64) d1 += hv[i] * w1[i];
  if (cl > 0) {
    const float* w2 = weight + (size_t)t * HH;
    for (int i = lane; i < HH; i += 64) d2 += hv[i] * w2[i];
  }
#pragma unroll
  for (int m = 1; m < 64; m <<= 1) {
    d1 += __shfl_xor(d1, m);
    d2 += __shfl_xor(d2, m);
  }
  if (lane == 0) {
    float loss = logf(s0) - (d1 + b1);
    if (cl > 0) loss += logf(st) - (d2 + bias[t]);
    losses[row] = loss;
  }
}

__global__ void meanloss(const float* __restrict__ losses, float* __restrict__ out) {
  __shared__ float red[256];
  float s = 0.f;
  for (int i = threadIdx.x; i < NROWS; i += 256) s += losses[i];
  red[threadIdx.x] = s;
  __syncthreads();
  for (int st = 128; st > 0; st >>= 1) {
    if ((int)threadIdx.x < st) red[threadIdx.x] += red[threadIdx.x + st];
    __syncthreads();
  }
  if (threadIdx.x == 0) out[0] = red[0] / (float)NROWS;
}

extern "C" void kernel_launch(void* const* d_in, const int* in_sizes, int n_in,
                              void* d_out, int out_size, void* d_ws, size_t ws_size,
                              hipStream_t stream) {
  const float* weight = (const float*)d_in[0];
  const float* bias = (const float*)d_in[1];
  const float* hiddens = (const float*)d_in[2];
  const float* tails = (const float*)d_in[3];
  const float* tail_bias = (const float*)d_in[4];
  const int* targets = (const int*)d_in[5];
  float* out = (float*)d_out;

  char* ws = (char*)d_ws;
  unsigned char* Wf = (unsigned char*)ws;                      // 50176*1024 = 51,380,224
  unsigned char* Hf = (unsigned char*)(ws + 51380224);         //  4,194,304
  unsigned char* Hc1 = (unsigned char*)(ws + 55574528);        //  4,194,304
  unsigned char* Hc2 = (unsigned char*)(ws + 59768832);        //  4,194,304 (contig w/ Hc1)
  float* ph = (float*)(ws + 63963136);                         //  4096*64*4  = 1,048,576
  float* pt1 = (float*)(ws + 65011712);                        //  4096*250*4 = 4,096,000
  float* pt2 = (float*)(ws + 69107712);                        //  4096*470*4 = 7,700,480
  float* biasr = (float*)(ws + 76808192);                      //  50176*4    = 200,704
  int* cidx = (int*)(ws + 77008896);                           //  16,384
  int* counts = (int*)(ws + 77025280);                         //  64
  float* losses = (float*)(ws + 77025344);                     //  16,384

  hipLaunchKernelGGL(convW, dim3(2048), dim3(256), 0, stream, weight, tails, Wf);
  hipLaunchKernelGGL(biasK, dim3((VPAD + 255) / 256), dim3(256), 0, stream, bias,
                     tail_bias, biasr);
  hipLaunchKernelGGL(convH, dim3(512), dim3(256), 0, stream, hiddens, Hf);
  hipLaunchKernelGGL(scanK, dim3(1), dim3(1024), 0, stream, targets, cidx, counts);
  hipLaunchKernelGGL(zeroHc, dim3(1024), dim3(256), 0, stream, (uint4*)Hc1);
  hipLaunchKernelGGL(gatherK, dim3(NROWS / 4), dim3(256), 0, stream, Hf, targets, cidx,
                     Hc1, Hc2);
  // head: all rows x cols [0,4002) (padded to 4096)
  hipLaunchKernelGGL(gemm_lse, dim3(NRT * CT_HEAD), dim3(256), 0, stream, Hf, Wf,
                     CT_HEAD, 0, CL_HEAD, biasr, ph, counts, 2);
  // tail1: cluster-1 rows x cols [4002,20002)
  hipLaunchKernelGGL(gemm_lse, dim3(NRT * CT_T1), dim3(256), 0, stream, Hc1, Wf, CT_T1,
                     CB_T1, CL_T1, biasr, pt1, counts, 0);
  // tail2: cluster-2 rows x cols [20002,50002) (padded to 30080)
  hipLaunchKernelGGL(gemm_lse, dim3(NRT * CT_T2), dim3(256), 0, stream, Hc2, Wf, CT_T2,
                     CB_T2, CL_T2, biasr, pt2, counts, 1);
  hipLaunchKernelGGL(rowloss, dim3(NROWS / 4), dim3(256), 0, stream, ph, pt1, pt2, cidx,
                     hiddens, weight, bias, tails, tail_bias, targets, losses);
  hipLaunchKernelGGL(meanloss, dim3(1), dim3(256), 0, stream, losses, out);
}